// Round 15
// baseline (307.834 us; speedup 1.0000x reference)
//
#include <hip/hip_runtime.h>
#include <hip/hip_fp16.h>
#include <math.h>

#define PI_F      3.14159265358979323846f
#define TWO_PI_F  6.28318530717958647692f
#define PI4_F     0.78539816339744830962f   // pi/4 == ROT_SCALE == 2pi/8

typedef _Float16 f16x8 __attribute__((ext_vector_type(8)));
typedef float    f32x4 __attribute__((ext_vector_type(4)));

__device__ __forceinline__ float sgn(float t) {
    return (t > 0.f) ? 1.f : ((t < 0.f) ? -1.f : 0.f);
}

__device__ __forceinline__ float b2(float x) {
    float a = x - 0.5f;
    float b = x - 1.5f;
    float c = 1.f + 2.f * x;
    float d = 3.f + 2.f * x;
    return (-3.f * a * a * sgn(0.5f - x)
            + b * b * sgn(1.5f - x)
            - 0.75f * c * c * sgn(0.5f + x)
            + 0.25f * d * d * sgn(1.5f + x)) * 0.25f;
}

// ks_h[t][O][I] fp16.  t = dx*5+dy, O = r0*8+o, I = i*8+r
__global__ void build_ks_kernel(const float* __restrict__ w, __half* __restrict__ ksh) {
    int g = blockIdx.x * 256 + threadIdx.x;
    if (g >= 64 * 32 * 25) return;
    int O = g & 63;
    int rest = g >> 6;
    int t = rest % 25;
    int I = rest / 25;
    int r0 = O >> 3, o = O & 7;
    int i = I >> 3, r = I & 7;
    int x = t / 5, y = t % 5;

    float theta = -(float)r0 * PI4_F;
    float cth = cosf(theta), sth = sinf(theta);
    float fx = (float)(x - 2), fy = (float)(y - 2);
    float xc = fx * cth - fy * sth;
    float yc = fx * sth + fy * cth;

    float rotv[8];
    float rs = (float)r * PI4_F + theta;
    #pragma unroll
    for (int mr = 0; mr < 8; ++mr) {
        float v = (float)mr * PI4_F - rs + PI_F;
        float md = fmodf(v, TWO_PI_F);
        if (md < 0.f) md += TWO_PI_F;
        rotv[mr] = b2((md - PI_F) / PI4_F);
    }

    float sum = 0.f;
    for (int mx = 0; mx < 25; ++mx) {
        float cx = (float)(mx / 5 - 2);
        float cy = (float)(mx % 5 - 2);
        float bx = b2(cx - xc) * b2(cy - yc);
        if (bx != 0.f) {
            const float* wp = w + (size_t)(i * 200 + mx * 8) * 8 + o;
            #pragma unroll
            for (int mr = 0; mr < 8; ++mr)
                sum = fmaf(bx * rotv[mr], wp[mr * 8], sum);
        }
    }
    ksh[(size_t)(t * 64 + O) * 32 + I] = __float2half(sum);
}

// Cross-tile pipelined implicit-GEMM conv. 256 blocks (1/CU), 512 threads
// (8 waves). Each block owns 4 consecutive 16h x 32w tiles (same batch/h-strip).
// LDS: double-buffered xt[2][slot(4)][720 px (20x36 halo)] uint4, stride 721
// (92.3 KB total). Per iteration s:
//   issue tile-(s+1) global loads -> regs  (48 f32/thread, static arrays)
//   taps 0..11 on buf[s&1]  (HBM latency hides here)
//   cvt + ds_write prefetched tile -> buf[(s+1)&1]  (other buffer: no barrier)
//   taps 12..24, async stores, barrier, swap.
// Wave owns 2 h-rows = 4 M-tiles x 4 N-tiles (acc 64 f32) to leave register
// room for the stage block (~190 unified regs -> 2 waves/SIMD).
__global__ __launch_bounds__(512, 1) void conv_pipe_kernel(const float* __restrict__ X,
                                                           const __half* __restrict__ ksh,
                                                           float* __restrict__ out) {
    __shared__ uint4 xt[2][4 * 721];    // 2 x 46,144 B

    int bid = blockIdx.x;
    int b   = bid >> 5;               // 8 batches, b-major
    int rem = bid & 31;
    int h0  = (rem >> 1) << 4;        // 16 h-strips of 16
    int wg  = (rem & 1) << 2;         // w-strip group: strips wg..wg+3
    int tid = threadIdx.x;

    const float* Xb = X + (size_t)b * 32 * 65536;

    float pk[6][8];                   // prefetched stage data (48 f32)

    auto stage_load = [&](int w0s) {
        #pragma unroll
        for (int k = 0; k < 6; ++k) {
            int lin = tid + k * 512;
            if (lin < 2880) {
                int slot = lin / 720;
                int p    = lin - slot * 720;
                int r = p / 36, c = p - (p / 36) * 36;
                int gh = h0 + r - 2;
                int gw = w0s + c - 2;
                if ((unsigned)gh < 256u && (unsigned)gw < 256u) {
                    const float* src = Xb + (size_t)slot * 8 * 65536 + gh * 256 + gw;
                    #pragma unroll
                    for (int j = 0; j < 8; ++j) pk[k][j] = src[j * 65536];
                } else {
                    #pragma unroll
                    for (int j = 0; j < 8; ++j) pk[k][j] = 0.f;
                }
            }
        }
    };

    auto stage_write = [&](uint4* dstbuf) {
        #pragma unroll
        for (int k = 0; k < 6; ++k) {
            int lin = tid + k * 512;
            if (lin < 2880) {
                int slot = lin / 720;
                int p    = lin - slot * 720;
                union { __half hh[8]; uint4 u; } q;
                #pragma unroll
                for (int j = 0; j < 8; ++j) q.hh[j] = __float2half(pk[k][j]);
                dstbuf[slot * 721 + p] = q.u;
            }
        }
    };

    int wave = tid >> 6, lane = tid & 63;
    int lO = lane & 15, ks4 = lane >> 4;
    int bidx = lO * 4 + ks4;
    const uint4* ksq = (const uint4*)ksh;

    int baseA[4];
    #pragma unroll
    for (int m = 0; m < 4; ++m)
        baseA[m] = 721 * ks4 + (wave * 2 + (m >> 1)) * 36 + (m & 1) * 16 + lO;

    // ---- prologue: stage tile 0 ----
    stage_load(wg << 5);
    stage_write(&xt[0][0]);
    __syncthreads();

    #pragma unroll 1
    for (int s = 0; s < 4; ++s) {
        const uint4* cbuf = &xt[s & 1][0];
        uint4* nbuf = &xt[(s + 1) & 1][0];
        int w0s = (wg + s) << 5;

        if (s < 3) stage_load((wg + s + 1) << 5);   // HBM latency hides under taps

        f32x4 acc[4][4] = {};
        f16x8 Bf[2][4];
        #pragma unroll
        for (int n = 0; n < 4; ++n)
            Bf[0][n] = __builtin_bit_cast(f16x8, ksq[n * 64 + bidx]);

        // ---- taps 0..11 ----
        #pragma unroll
        for (int t = 0; t < 12; ++t) {
            const int cur = t & 1, nxt = cur ^ 1;
            const int aoff = (t / 5) * 36 + (t % 5);
            f16x8 Af[4];
            #pragma unroll
            for (int m = 0; m < 4; ++m)
                Af[m] = __builtin_bit_cast(f16x8, cbuf[baseA[m] + aoff]);
            #pragma unroll
            for (int n = 0; n < 4; ++n)
                Bf[nxt][n] = __builtin_bit_cast(f16x8, ksq[(t + 1) * 256 + n * 64 + bidx]);
            #pragma unroll
            for (int m = 0; m < 4; ++m) {
                #pragma unroll
                for (int n = 0; n < 4; ++n)
                    acc[m][n] = __builtin_amdgcn_mfma_f32_16x16x32_f16(Af[m], Bf[cur][n], acc[m][n], 0, 0, 0);
            }
        }

        // ---- mid: write prefetched tile into the other buffer ----
        if (s < 3) stage_write(nbuf);

        // ---- taps 12..24 ----
        #pragma unroll
        for (int t = 12; t < 25; ++t) {
            const int cur = t & 1, nxt = cur ^ 1;
            const int aoff = (t / 5) * 36 + (t % 5);
            f16x8 Af[4];
            #pragma unroll
            for (int m = 0; m < 4; ++m)
                Af[m] = __builtin_bit_cast(f16x8, cbuf[baseA[m] + aoff]);
            if (t < 24) {
                #pragma unroll
                for (int n = 0; n < 4; ++n)
                    Bf[nxt][n] = __builtin_bit_cast(f16x8, ksq[(t + 1) * 256 + n * 64 + bidx]);
            }
            #pragma unroll
            for (int m = 0; m < 4; ++m) {
                #pragma unroll
                for (int n = 0; n < 4; ++n)
                    acc[m][n] = __builtin_amdgcn_mfma_f32_16x16x32_f16(Af[m], Bf[cur][n], acc[m][n], 0, 0, 0);
            }
        }

        // ---- stores: out[b][O&7][O>>3][h][w] * (2pi/8); async, full lines ----
        #pragma unroll
        for (int m = 0; m < 4; ++m) {
            int gh  = h0 + wave * 2 + (m >> 1);
            int gwb = w0s + (m & 1) * 16 + ks4 * 4;
            #pragma unroll
            for (int n = 0; n < 4; ++n) {
                int O = n * 16 + lO;
                float* op = out + (((size_t)(b * 8 + (O & 7)) * 8 + (O >> 3)) << 16)
                                + gh * 256 + gwb;
                *(f32x4*)op = acc[m][n] * PI4_F;
            }
        }

        __syncthreads();
    }
}

extern "C" void kernel_launch(void* const* d_in, const int* in_sizes, int n_in,
                              void* d_out, int out_size, void* d_ws, size_t ws_size,
                              hipStream_t stream) {
    const float* X = (const float*)d_in[0];       // (8, 4, 8, 256, 256) f32
    const float* w = (const float*)d_in[1];       // (4, 200, 8) f32
    float* outp = (float*)d_out;                  // (8, 8, 8, 256, 256) f32
    __half* ksh = (__half*)d_ws;                  // 102.4 KB

    build_ks_kernel<<<200, 256, 0, stream>>>(w, ksh);
    conv_pipe_kernel<<<256, 512, 0, stream>>>(X, ksh, outp);
}

// Round 16
// 242.193 us; speedup vs baseline: 1.2710x; 1.2710x over previous
//
#include <hip/hip_runtime.h>
#include <hip/hip_fp16.h>
#include <math.h>

#define PI_F      3.14159265358979323846f
#define TWO_PI_F  6.28318530717958647692f
#define PI4_F     0.78539816339744830962f   // pi/4 == ROT_SCALE == 2pi/8

typedef _Float16 f16x8 __attribute__((ext_vector_type(8)));
typedef float    f32x4 __attribute__((ext_vector_type(4)));

__device__ __forceinline__ float sgn(float t) {
    return (t > 0.f) ? 1.f : ((t < 0.f) ? -1.f : 0.f);
}

__device__ __forceinline__ float b2(float x) {
    float a = x - 0.5f;
    float b = x - 1.5f;
    float c = 1.f + 2.f * x;
    float d = 3.f + 2.f * x;
    return (-3.f * a * a * sgn(0.5f - x)
            + b * b * sgn(1.5f - x)
            - 0.75f * c * c * sgn(0.5f + x)
            + 0.25f * d * d * sgn(1.5f + x)) * 0.25f;
}

// ks_h[t][O][I] fp16.  t = dx*5+dy, O = r0*8+o, I = i*8+r
__global__ void build_ks_kernel(const float* __restrict__ w, __half* __restrict__ ksh) {
    int g = blockIdx.x * 256 + threadIdx.x;
    if (g >= 64 * 32 * 25) return;
    int O = g & 63;
    int rest = g >> 6;
    int t = rest % 25;
    int I = rest / 25;
    int r0 = O >> 3, o = O & 7;
    int i = I >> 3, r = I & 7;
    int x = t / 5, y = t % 5;

    float theta = -(float)r0 * PI4_F;
    float cth = cosf(theta), sth = sinf(theta);
    float fx = (float)(x - 2), fy = (float)(y - 2);
    float xc = fx * cth - fy * sth;
    float yc = fx * sth + fy * cth;

    float rotv[8];
    float rs = (float)r * PI4_F + theta;
    #pragma unroll
    for (int mr = 0; mr < 8; ++mr) {
        float v = (float)mr * PI4_F - rs + PI_F;
        float md = fmodf(v, TWO_PI_F);
        if (md < 0.f) md += TWO_PI_F;
        rotv[mr] = b2((md - PI_F) / PI4_F);
    }

    float sum = 0.f;
    for (int mx = 0; mx < 25; ++mx) {
        float cx = (float)(mx / 5 - 2);
        float cy = (float)(mx % 5 - 2);
        float bx = b2(cx - xc) * b2(cy - yc);
        if (bx != 0.f) {
            const float* wp = w + (size_t)(i * 200 + mx * 8) * 8 + o;
            #pragma unroll
            for (int mr = 0; mr < 8; ++mr)
                sum = fmaf(bx * rotv[mr], wp[mr * 8], sum);
        }
    }
    ksh[(size_t)(t * 64 + O) * 32 + I] = __float2half(sum);
}

// Cross-tile pipelined implicit-GEMM conv, spill-proof variant.
// 256 blocks (1/CU), 512 threads (8 waves). Block owns 4 tiles of 16h x 32w
// (same batch & h-strip). LDS double buffer xt[2][4 slot][720 px] uint4,
// stride 721 (92.3 KB). The 6 stage tasks of tile s+1 are woven into the
// 25-tap loop of tile s: task-k loads issue at tap 4k-4, cvt+ds_write (into
// the OTHER buffer) at tap 4k+3 -> ~4 taps of MFMA hide the HBM latency.
// Only 2 tasks in flight (fA/fB, 16 VGPR) — no scratch (r15's failure).
// Wave owns 2 h-rows = 4 M-tiles x 4 N-tiles, 16 MFMA/tap; one barrier/tile.
__global__ __launch_bounds__(512, 1) void conv_pipe_kernel(const float* __restrict__ X,
                                                           const __half* __restrict__ ksh,
                                                           float* __restrict__ out) {
    __shared__ uint4 xt[2][4 * 721];    // 2 x 46,144 B

    int bid = blockIdx.x;
    int b   = bid >> 5;               // 8 batches, b-major
    int rem = bid & 31;
    int h0  = (rem >> 1) << 4;        // 16 h-strips of 16
    int wg  = (rem & 1) << 2;         // w-strip group: strips wg..wg+3
    int tid = threadIdx.x;

    const float* Xb = X + (size_t)b * 32 * 65536;

    float fA[8], fB[8];               // 2 stage tasks in flight (16 VGPR)

#define STAGE_LOAD(K, F) do {                                                  \
    int lin_ = tid + (K) * 512;                                                \
    if (lin_ < 2880) {                                                         \
        int slot_ = lin_ / 720;                                                \
        int p_    = lin_ - slot_ * 720;                                        \
        int r_ = p_ / 36, c_ = p_ - (p_ / 36) * 36;                            \
        int gh_ = h0 + r_ - 2, gw_ = w0n + c_ - 2;                             \
        if ((unsigned)gh_ < 256u && (unsigned)gw_ < 256u) {                    \
            const float* src_ = Xb + (size_t)slot_ * 8 * 65536 + gh_ * 256 + gw_; \
            _Pragma("unroll") for (int j_ = 0; j_ < 8; ++j_) F[j_] = src_[j_ * 65536]; \
        } else {                                                               \
            _Pragma("unroll") for (int j_ = 0; j_ < 8; ++j_) F[j_] = 0.f;      \
        }                                                                      \
    } } while (0)

#define STAGE_WRITE(K, F) do {                                                 \
    int lin_ = tid + (K) * 512;                                                \
    if (lin_ < 2880) {                                                         \
        int slot_ = lin_ / 720;                                                \
        int p_    = lin_ - slot_ * 720;                                        \
        union { __half hh[8]; uint4 u; } q_;                                   \
        _Pragma("unroll") for (int j_ = 0; j_ < 8; ++j_) q_.hh[j_] = __float2half(F[j_]); \
        nbuf[slot_ * 721 + p_] = q_.u;                                         \
    } } while (0)

    int wave = tid >> 6, lane = tid & 63;
    int lO = lane & 15, ks4 = lane >> 4;
    int bidx = lO * 4 + ks4;
    const uint4* ksq = (const uint4*)ksh;

    int baseA[4];
    #pragma unroll
    for (int m = 0; m < 4; ++m)
        baseA[m] = 721 * ks4 + (wave * 2 + (m >> 1)) * 36 + (m & 1) * 16 + lO;

    // ---- prologue: stage tile 0 directly (load->cvt->write) ----
    {
        uint4* nbuf = &xt[0][0];
        int w0n = wg << 5;
        #pragma unroll
        for (int k = 0; k < 6; ++k) {
            STAGE_LOAD(k, fA);
            STAGE_WRITE(k, fA);
        }
    }
    __syncthreads();

    #pragma unroll 1
    for (int s = 0; s < 4; ++s) {
        const uint4* cbuf = &xt[s & 1][0];
        uint4* nbuf = &xt[(s + 1) & 1][0];
        int w0s = (wg + s) << 5;
        int w0n = (wg + s + 1) << 5;
        const bool staging = (s < 3);

        f32x4 acc[4][4] = {};
        f16x8 Bf[2][4];
        #pragma unroll
        for (int n = 0; n < 4; ++n)
            Bf[0][n] = __builtin_bit_cast(f16x8, ksq[n * 64 + bidx]);

        if (staging) STAGE_LOAD(0, fA);   // task0 loads in flight before tap 0

        #pragma unroll
        for (int t = 0; t < 25; ++t) {
            const int cur = t & 1, nxt = cur ^ 1;
            const int aoff = (t / 5) * 36 + (t % 5);

            f16x8 Af[4];
            #pragma unroll
            for (int m = 0; m < 4; ++m)
                Af[m] = __builtin_bit_cast(f16x8, cbuf[baseA[m] + aoff]);

            if (t < 24) {
                #pragma unroll
                for (int n = 0; n < 4; ++n)
                    Bf[nxt][n] = __builtin_bit_cast(f16x8, ksq[(t + 1) * 256 + n * 64 + bidx]);
            }

            #pragma unroll
            for (int m = 0; m < 4; ++m) {
                #pragma unroll
                for (int n = 0; n < 4; ++n)
                    acc[m][n] = __builtin_amdgcn_mfma_f32_16x16x32_f16(Af[m], Bf[cur][n], acc[m][n], 0, 0, 0);
            }

            // weave stage tasks between tap groups (static t -> compile-time)
            if (staging) {
                if (t == 3)  { STAGE_LOAD(1, fB); STAGE_WRITE(0, fA); }
                if (t == 7)  { STAGE_LOAD(2, fA); STAGE_WRITE(1, fB); }
                if (t == 11) { STAGE_LOAD(3, fB); STAGE_WRITE(2, fA); }
                if (t == 15) { STAGE_LOAD(4, fA); STAGE_WRITE(3, fB); }
                if (t == 19) { STAGE_LOAD(5, fB); STAGE_WRITE(4, fA); }
                if (t == 23) { STAGE_WRITE(5, fB); }
            }
        }

        // ---- stores: out[b][O&7][O>>3][h][w] * (2pi/8); full 128-B lines ----
        #pragma unroll
        for (int m = 0; m < 4; ++m) {
            int gh  = h0 + wave * 2 + (m >> 1);
            int gwb = w0s + (m & 1) * 16 + ks4 * 4;
            #pragma unroll
            for (int n = 0; n < 4; ++n) {
                int O = n * 16 + lO;
                float* op = out + (((size_t)(b * 8 + (O & 7)) * 8 + (O >> 3)) << 16)
                                + gh * 256 + gwb;
                *(f32x4*)op = acc[m][n] * PI4_F;
            }
        }

        __syncthreads();
    }
#undef STAGE_LOAD
#undef STAGE_WRITE
}

extern "C" void kernel_launch(void* const* d_in, const int* in_sizes, int n_in,
                              void* d_out, int out_size, void* d_ws, size_t ws_size,
                              hipStream_t stream) {
    const float* X = (const float*)d_in[0];       // (8, 4, 8, 256, 256) f32
    const float* w = (const float*)d_in[1];       // (4, 200, 8) f32
    float* outp = (float*)d_out;                  // (8, 8, 8, 256, 256) f32
    __half* ksh = (__half*)d_ws;                  // 102.4 KB

    build_ks_kernel<<<200, 256, 0, stream>>>(w, ksh);
    conv_pipe_kernel<<<256, 512, 0, stream>>>(X, ksh, outp);
}